// Round 1
// baseline (422.873 us; speedup 1.0000x reference)
//
#include <hip/hip_runtime.h>
#include <stdint.h>

// Problem constants (B=4, S=2048, D=4096)
#define DDIM 4096
#define MTOK 8192
#define KTILES (DDIM / 128)   // 32 K-tiles of BK=128

typedef __attribute__((ext_vector_type(4))) int i32x4;
typedef __attribute__((ext_vector_type(16))) int i32x16;

__device__ __forceinline__ void async16(const void* g, void* l) {
    __builtin_amdgcn_global_load_lds(
        (const __attribute__((address_space(1))) unsigned int*)g,
        (__attribute__((address_space(3))) unsigned int*)l,
        16, 0, 0);
}

// ---------------- Fused quantization kernel (unchanged) ----------------
// Blocks [0, MTOK): activation rows, t = x*scales
// Blocks [MTOK, MTOK+DDIM): weight rows, t = w/scales (also writes bq)
__global__ __launch_bounds__(256) void quant_all(
    const float* __restrict__ x, const float* __restrict__ weight,
    const float* __restrict__ scales,
    signed char* __restrict__ qx, float* __restrict__ sx,
    signed char* __restrict__ qw, float* __restrict__ sw,
    const float* __restrict__ bias, float* __restrict__ bq)
{
    __shared__ float red[4];
    const int tid = threadIdx.x;
    const bool is_x = blockIdx.x < MTOK;
    const int row = is_x ? blockIdx.x : (blockIdx.x - MTOK);
    const float* src = is_x ? (x + (size_t)row * DDIM) : (weight + (size_t)row * DDIM);
    signed char* q = is_x ? qx : qw;
    float* srow = is_x ? sx : sw;

    const float4* s4 = (const float4*)scales;
    const float4* x4 = (const float4*)src;

    float4 v[4];
    float am = 0.0f;
#pragma unroll
    for (int j = 0; j < 4; ++j) {
        float4 a = x4[tid + j * 256];
        float4 s = s4[tid + j * 256];
        float4 r;
        if (is_x) { r.x = a.x * s.x; r.y = a.y * s.y; r.z = a.z * s.z; r.w = a.w * s.w; }
        else      { r.x = a.x / s.x; r.y = a.y / s.y; r.z = a.z / s.z; r.w = a.w / s.w; }
        v[j] = r;
        am = fmaxf(am, fmaxf(fmaxf(fabsf(r.x), fabsf(r.y)),
                             fmaxf(fabsf(r.z), fabsf(r.w))));
    }
#pragma unroll
    for (int off = 32; off > 0; off >>= 1)
        am = fmaxf(am, __shfl_xor(am, off, 64));
    if ((tid & 63) == 0) red[tid >> 6] = am;
    __syncthreads();
    am = fmaxf(fmaxf(red[0], red[1]), fmaxf(red[2], red[3]));
    am = fmaxf(am, 1e-8f);

    const float sc = 127.0f / am;
    uint32_t* qrow = (uint32_t*)(q + (size_t)row * DDIM);
#pragma unroll
    for (int j = 0; j < 4; ++j) {
        int q0 = (int)fminf(127.0f, fmaxf(-127.0f, rintf(v[j].x * sc)));
        int q1 = (int)fminf(127.0f, fmaxf(-127.0f, rintf(v[j].y * sc)));
        int q2 = (int)fminf(127.0f, fmaxf(-127.0f, rintf(v[j].z * sc)));
        int q3 = (int)fminf(127.0f, fmaxf(-127.0f, rintf(v[j].w * sc)));
        qrow[tid + j * 256] = (uint32_t)(q0 & 0xff) | ((uint32_t)(q1 & 0xff) << 8) |
                              ((uint32_t)(q2 & 0xff) << 16) | ((uint32_t)(q3 & 0xff) << 24);
    }
    if (tid == 0) {
        srow[row] = am * (1.0f / 127.0f);
        if (!is_x) bq[row] = bias[row] / scales[row];
    }
}

// ---------------- int8 GEMM, 256x256 tile, 8-wave phased pipeline ----------------
// out[m,n] = (sum_k qx[m,k]*qw[n,k]) * sx[m]*sw[n] + bq[n]
//
// Structure (ported 256^2 8-phase template, i8 variant):
//   BM=BN=256, BK=128, 512 threads = 8 waves in 2(M)x4(N); per-wave C = 128x64
//   = 4x2 of 32x32 i8 MFMA tiles. LDS = 2 x (A 32KB + B 32KB) = 128 KiB dbuf.
//   Per K-tile: issue ALL 8 global_load_lds for tile kt+1 into buf^1 (max
//   latency window), then s_waitcnt vmcnt(8) -- counted, never 0 in the main
//   loop, so next-tile loads stay in flight across the barrier -- then 4
//   phases of {6 ds_read_b128 ; s_barrier ; setprio(1) 8xMFMA setprio(0) ;
//   s_barrier}. sched_barrier(0) pins ds_reads below the tile-ready barrier
//   (race with the async LDS writes otherwise).
//
// LDS rows are 128 B (= 32 banks); 16 B chunk kc of row r stored at chunk
// kc ^ (r&7) (swizzle applied on the GLOBAL fetch address since
// global_load_lds dst is fixed base+lane*16). A and B use the identical
// k-chunk permutation, so the MFMA contraction is unchanged (carried over
// verified from the 128^2 kernel).
__global__ __launch_bounds__(512, 2) void gemm_i8(
    const signed char* __restrict__ qx, const signed char* __restrict__ qw,
    const float* __restrict__ sx, const float* __restrict__ sw,
    const float* __restrict__ bq, float* __restrict__ out)
{
    __shared__ __align__(16) signed char sA[2][256 * 128];
    __shared__ __align__(16) signed char sB[2][256 * 128];

    const int K = DDIM, N = DDIM;
    const int tid  = threadIdx.x;
    const int bm   = blockIdx.y;
    const int bn   = blockIdx.x;
    const int wave = tid >> 6;
    const int lane = tid & 63;
    const int wm   = (wave >> 2) << 7;  // 0 or 128: wave M offset in 256 tile
    const int wn   = (wave & 3) << 6;   // 0,64,128,192: wave N offset
    const int r5   = lane & 31;         // fragment row within 32-row tile
    const int hi   = lane >> 5;         // k-half selector

    const signed char* Ab = qx + (size_t)bm * 256 * K;
    const signed char* Bb = qw + (size_t)bn * 256 * K;

    // Staging: thread covers LDS bytes p = tid*16 + c*8192, c in 0..3 per matrix.
    // p -> row = p>>7 = (tid>>3) + 64c ; chunk-in-row cir = tid&7.
    // Fetch global k-chunk kc = cir ^ (row & 7).
    const int srow = tid >> 3;
    const int cir  = tid & 7;

    // Reader chunk byte offsets: k-quarter kq -> global chunk kq*2+hi, stored at
    // (kq*2+hi) ^ (r5&7); byte offset within row = that * 16.
    int roff[4];
#pragma unroll
    for (int kq = 0; kq < 4; ++kq)
        roff[kq] = (((kq * 2 + hi) ^ (r5 & 7)) << 4);

    i32x16 acc[4][2] = {};

    // Prologue: stage K-tile 0 into buffer 0.
#pragma unroll
    for (int c = 0; c < 4; ++c) {
        const int row = srow + 64 * c;
        const int kc  = cir ^ (row & 7);
        const int p   = tid * 16 + c * 8192;
        async16(Ab + (size_t)row * K + kc * 16, &sA[0][p]);
        async16(Bb + (size_t)row * K + kc * 16, &sB[0][p]);
    }

    for (int kt = 0; kt < KTILES; ++kt) {
        const int cur = kt & 1;

        if (kt + 1 < KTILES) {
            // Issue next K-tile's 8 staging loads into the other buffer.
            // Safe: buf[cur^1] was last read in tile kt-1, whose reads completed
            // (lgkmcnt before its final MFMAs) before this point in program order.
            const int k0n = (kt + 1) * 128;
#pragma unroll
            for (int c = 0; c < 4; ++c) {
                const int row = srow + 64 * c;
                const int kc  = cir ^ (row & 7);
                const int p   = tid * 16 + c * 8192;
                async16(Ab + (size_t)row * K + k0n + kc * 16, &sA[cur ^ 1][p]);
                async16(Bb + (size_t)row * K + k0n + kc * 16, &sB[cur ^ 1][p]);
            }
            // 16 outstanding: wait for the oldest 8 (= tile kt), keep 8 in flight.
            asm volatile("s_waitcnt vmcnt(8)" ::: "memory");
        } else {
            asm volatile("s_waitcnt vmcnt(0)" ::: "memory");
        }
        __builtin_amdgcn_s_barrier();          // tile kt visible to all waves
        __builtin_amdgcn_sched_barrier(0);     // pin: no ds_read hoists above

        const signed char* sAc = sA[cur];
        const signed char* sBc = sB[cur];

#pragma unroll
        for (int p = 0; p < 4; ++p) {
            i32x4 a0 = *(const i32x4*)&sAc[(wm +      r5) * 128 + roff[p]];
            i32x4 a1 = *(const i32x4*)&sAc[(wm + 32 + r5) * 128 + roff[p]];
            i32x4 a2 = *(const i32x4*)&sAc[(wm + 64 + r5) * 128 + roff[p]];
            i32x4 a3 = *(const i32x4*)&sAc[(wm + 96 + r5) * 128 + roff[p]];
            i32x4 b0 = *(const i32x4*)&sBc[(wn +      r5) * 128 + roff[p]];
            i32x4 b1 = *(const i32x4*)&sBc[(wn + 32 + r5) * 128 + roff[p]];

            __builtin_amdgcn_s_barrier();      // phase: reads issued -> MFMA burst

            __builtin_amdgcn_s_setprio(1);
            acc[0][0] = __builtin_amdgcn_mfma_i32_32x32x32_i8(a0, b0, acc[0][0], 0, 0, 0);
            acc[0][1] = __builtin_amdgcn_mfma_i32_32x32x32_i8(a0, b1, acc[0][1], 0, 0, 0);
            acc[1][0] = __builtin_amdgcn_mfma_i32_32x32x32_i8(a1, b0, acc[1][0], 0, 0, 0);
            acc[1][1] = __builtin_amdgcn_mfma_i32_32x32x32_i8(a1, b1, acc[1][1], 0, 0, 0);
            acc[2][0] = __builtin_amdgcn_mfma_i32_32x32x32_i8(a2, b0, acc[2][0], 0, 0, 0);
            acc[2][1] = __builtin_amdgcn_mfma_i32_32x32x32_i8(a2, b1, acc[2][1], 0, 0, 0);
            acc[3][0] = __builtin_amdgcn_mfma_i32_32x32x32_i8(a3, b0, acc[3][0], 0, 0, 0);
            acc[3][1] = __builtin_amdgcn_mfma_i32_32x32x32_i8(a3, b1, acc[3][1], 0, 0, 0);
            __builtin_amdgcn_s_setprio(0);

            if (p < 3) __builtin_amdgcn_s_barrier();  // phase end (p=3 flows into
                                                      // next tile's stage+barrier)
        }
    }

    // Epilogue: 32x32 C/D layout col(n) = lane&31, row(m) = (reg&3) + 8*(reg>>2) + 4*hi
#pragma unroll
    for (int mi = 0; mi < 4; ++mi) {
        const int mbase = bm * 256 + wm + mi * 32 + 4 * hi;
        float sxv[16];
#pragma unroll
        for (int r = 0; r < 16; ++r)
            sxv[r] = sx[mbase + (r & 3) + 8 * (r >> 2)];
#pragma unroll
        for (int nj = 0; nj < 2; ++nj) {
            const int n = bn * 256 + wn + nj * 32 + r5;
            const float swn = sw[n];
            const float bqn = bq[n];
#pragma unroll
            for (int r = 0; r < 16; ++r) {
                const int m = mbase + (r & 3) + 8 * (r >> 2);
                out[(size_t)m * N + n] = (float)acc[mi][nj][r] * sxv[r] * swn + bqn;
            }
        }
    }
}

extern "C" void kernel_launch(void* const* d_in, const int* in_sizes, int n_in,
                              void* d_out, int out_size, void* d_ws, size_t ws_size,
                              hipStream_t stream) {
    const float* x      = (const float*)d_in[0];  // [4,2048,4096]
    const float* weight = (const float*)d_in[1];  // [4096,4096]
    const float* bias   = (const float*)d_in[2];  // [4096]
    const float* scales = (const float*)d_in[3];  // [4096]
    float* out = (float*)d_out;                   // [4,2048,4096]

    char* ws = (char*)d_ws;
    signed char* qx = (signed char*)ws;                       // 8192*4096 = 33554432 B
    signed char* qw = (signed char*)(ws + 33554432);          // 4096*4096 = 16777216 B
    float* sx = (float*)(ws + 50331648);                      // 8192*4 B
    float* sw = (float*)(ws + 50364416);                      // 4096*4 B
    float* bq = (float*)(ws + 50380800);                      // 4096*4 B

    quant_all<<<MTOK + DDIM, 256, 0, stream>>>(x, weight, scales, qx, sx, qw, sw, bias, bq);

    dim3 grid(DDIM / 256, MTOK / 256);  // (16, 32) = 512 blocks, 1 per CU x 2 passes
    gemm_i8<<<grid, 512, 0, stream>>>(qx, qw, sx, sw, bq, out);
}

// Round 2
// 410.776 us; speedup vs baseline: 1.0294x; 1.0294x over previous
//
#include <hip/hip_runtime.h>
#include <stdint.h>

// Problem constants (B=4, S=2048, D=4096)
#define DDIM 4096
#define MTOK 8192
#define KTILES (DDIM / 128)   // 32 K-tiles of BK=128

typedef __attribute__((ext_vector_type(4))) int i32x4;
typedef __attribute__((ext_vector_type(16))) int i32x16;

__device__ __forceinline__ void async16(const void* g, void* l) {
    __builtin_amdgcn_global_load_lds(
        (const __attribute__((address_space(1))) unsigned int*)g,
        (__attribute__((address_space(3))) unsigned int*)l,
        16, 0, 0);
}

// ---------------- Fused quantization kernel (unchanged, ~35 us) ----------------
__global__ __launch_bounds__(256) void quant_all(
    const float* __restrict__ x, const float* __restrict__ weight,
    const float* __restrict__ scales,
    signed char* __restrict__ qx, float* __restrict__ sx,
    signed char* __restrict__ qw, float* __restrict__ sw,
    const float* __restrict__ bias, float* __restrict__ bq)
{
    __shared__ float red[4];
    const int tid = threadIdx.x;
    const bool is_x = blockIdx.x < MTOK;
    const int row = is_x ? blockIdx.x : (blockIdx.x - MTOK);
    const float* src = is_x ? (x + (size_t)row * DDIM) : (weight + (size_t)row * DDIM);
    signed char* q = is_x ? qx : qw;
    float* srow = is_x ? sx : sw;

    const float4* s4 = (const float4*)scales;
    const float4* x4 = (const float4*)src;

    float4 v[4];
    float am = 0.0f;
#pragma unroll
    for (int j = 0; j < 4; ++j) {
        float4 a = x4[tid + j * 256];
        float4 s = s4[tid + j * 256];
        float4 r;
        if (is_x) { r.x = a.x * s.x; r.y = a.y * s.y; r.z = a.z * s.z; r.w = a.w * s.w; }
        else      { r.x = a.x / s.x; r.y = a.y / s.y; r.z = a.z / s.z; r.w = a.w / s.w; }
        v[j] = r;
        am = fmaxf(am, fmaxf(fmaxf(fabsf(r.x), fabsf(r.y)),
                             fmaxf(fabsf(r.z), fabsf(r.w))));
    }
#pragma unroll
    for (int off = 32; off > 0; off >>= 1)
        am = fmaxf(am, __shfl_xor(am, off, 64));
    if ((tid & 63) == 0) red[tid >> 6] = am;
    __syncthreads();
    am = fmaxf(fmaxf(red[0], red[1]), fmaxf(red[2], red[3]));
    am = fmaxf(am, 1e-8f);

    const float sc = 127.0f / am;
    uint32_t* qrow = (uint32_t*)(q + (size_t)row * DDIM);
#pragma unroll
    for (int j = 0; j < 4; ++j) {
        int q0 = (int)fminf(127.0f, fmaxf(-127.0f, rintf(v[j].x * sc)));
        int q1 = (int)fminf(127.0f, fmaxf(-127.0f, rintf(v[j].y * sc)));
        int q2 = (int)fminf(127.0f, fmaxf(-127.0f, rintf(v[j].z * sc)));
        int q3 = (int)fminf(127.0f, fmaxf(-127.0f, rintf(v[j].w * sc)));
        qrow[tid + j * 256] = (uint32_t)(q0 & 0xff) | ((uint32_t)(q1 & 0xff) << 8) |
                              ((uint32_t)(q2 & 0xff) << 16) | ((uint32_t)(q3 & 0xff) << 24);
    }
    if (tid == 0) {
        srow[row] = am * (1.0f / 127.0f);
        if (!is_x) bq[row] = bias[row] / scales[row];
    }
}

// ---------------- int8 GEMM, 256x256 tile, fine-interleaved phased pipeline ----
// out[m,n] = (sum_k qx[m,k]*qw[n,k]) * sx[m]*sw[n] + bq[n]
//
// R2 structure (fine interleave per m196/m218; R1's coarse split was the
// measured -7..-27% failure mode):
//   BM=BN=256, BK=128, 512 threads = 8 waves 2(M)x4(N); per-wave C = 128x64
//   = 4x2 of 32x32x32 i8 MFMAs. LDS = 2 x 64 KB double buffer.
//   Per phase p in 0..3 (one k-quarter each):
//     issue 6 ds_read_b128 (a0..a3,b0,b1)      <- latency hides under barrier
//     p==0: issue 4 global_load_lds (next A)   <- youngest load gets >=2
//     p==1: issue 4 global_load_lds (next B)      phases (~1200cy) of cover
//     sched_barrier(0); s_barrier              <- reads/loads pinned above
//     s_waitcnt lgkmcnt(0); sched_barrier(0)   <- rule 18 fence
//     setprio(1); 8 MFMA; setprio(0)
//   One barrier per phase: waves may skew one region, so one wave's read
//   issue overlaps another's MFMA burst. Tile boundary: vmcnt(0)+barrier
//   (drain is ~free: youngest load issued 2 phases earlier, L2/LLC resident).
//
// LDS rows 128 B; 16 B chunk kc of row r stored at chunk kc ^ (r&7), swizzle
// applied on the GLOBAL fetch address (global_load_lds dst is base+lane*16).
// A and B use the identical k-chunk permutation -> contraction unchanged.
// Note: 4 extra cyc per ds_read_b128 in SQ_LDS_BANK_CONFLICT is the b128
// throughput floor (m134: 12 vs 8 cyc), not a swizzle defect.
__global__ __launch_bounds__(512, 2) void gemm_i8(
    const signed char* __restrict__ qx, const signed char* __restrict__ qw,
    const float* __restrict__ sx, const float* __restrict__ sw,
    const float* __restrict__ bq, float* __restrict__ out)
{
    __shared__ __align__(16) signed char sA[2][256 * 128];
    __shared__ __align__(16) signed char sB[2][256 * 128];

    const int K = DDIM, N = DDIM;
    const int tid  = threadIdx.x;
    const int bm   = blockIdx.y;
    const int bn   = blockIdx.x;
    const int wave = tid >> 6;
    const int lane = tid & 63;
    const int wm   = (wave >> 2) << 7;  // 0 or 128
    const int wn   = (wave & 3) << 6;   // 0,64,128,192
    const int r5   = lane & 31;
    const int hi   = lane >> 5;

    const signed char* Ab = qx + (size_t)bm * 256 * K;
    const signed char* Bb = qw + (size_t)bn * 256 * K;

    // Staging: thread covers LDS bytes p = tid*16 + c*8192, c in 0..3 per matrix.
    // p -> row = (tid>>3) + 64c ; chunk-in-row cir = tid&7. Fetch kc = cir^(row&7).
    const int srow = tid >> 3;
    const int cir  = tid & 7;

    int roff[4];
#pragma unroll
    for (int kq = 0; kq < 4; ++kq)
        roff[kq] = (((kq * 2 + hi) ^ (r5 & 7)) << 4);

    i32x16 acc[4][2] = {};

    // Prologue: stage K-tile 0 into buffer 0, drain, sync.
#pragma unroll
    for (int c = 0; c < 4; ++c) {
        const int row = srow + 64 * c;
        const int kc  = cir ^ (row & 7);
        const int p   = tid * 16 + c * 8192;
        async16(Ab + (size_t)row * K + kc * 16, &sA[0][p]);
        async16(Bb + (size_t)row * K + kc * 16, &sB[0][p]);
    }
    asm volatile("s_waitcnt vmcnt(0)" ::: "memory");
    __builtin_amdgcn_s_barrier();

    for (int kt = 0; kt < KTILES; ++kt) {
        const int cur = kt & 1;
        const signed char* sAc = sA[cur];
        const signed char* sBc = sB[cur];
        signed char* sAn = (signed char*)sA[cur ^ 1];
        signed char* sBn = (signed char*)sB[cur ^ 1];
        const int  k0n = (kt + 1) * 128;
        const bool pf  = (kt + 1 < KTILES);

#pragma unroll
        for (int p = 0; p < 4; ++p) {
            // ---- issue this phase's fragment reads (consumed after barrier) ----
            i32x4 a0 = *(const i32x4*)&sAc[(wm +      r5) * 128 + roff[p]];
            i32x4 a1 = *(const i32x4*)&sAc[(wm + 32 + r5) * 128 + roff[p]];
            i32x4 a2 = *(const i32x4*)&sAc[(wm + 64 + r5) * 128 + roff[p]];
            i32x4 a3 = *(const i32x4*)&sAc[(wm + 96 + r5) * 128 + roff[p]];
            i32x4 b0 = *(const i32x4*)&sBc[(wn +      r5) * 128 + roff[p]];
            i32x4 b1 = *(const i32x4*)&sBc[(wn + 32 + r5) * 128 + roff[p]];

            // ---- stage split: A-half in phase 0, B-half in phase 1 ----
            if (p == 0 && pf) {
#pragma unroll
                for (int c = 0; c < 4; ++c) {
                    const int row = srow + 64 * c;
                    const int kc  = cir ^ (row & 7);
                    async16(Ab + (size_t)row * K + k0n + kc * 16,
                            &sAn[tid * 16 + c * 8192]);
                }
            }
            if (p == 1 && pf) {
#pragma unroll
                for (int c = 0; c < 4; ++c) {
                    const int row = srow + 64 * c;
                    const int kc  = cir ^ (row & 7);
                    async16(Bb + (size_t)row * K + k0n + kc * 16,
                            &sBn[tid * 16 + c * 8192]);
                }
            }

            __builtin_amdgcn_sched_barrier(0);   // pin reads+loads above barrier
            __builtin_amdgcn_s_barrier();
            asm volatile("s_waitcnt lgkmcnt(0)" ::: "memory");
            __builtin_amdgcn_sched_barrier(0);   // rule 18: MFMAs stay below wait

            __builtin_amdgcn_s_setprio(1);
            acc[0][0] = __builtin_amdgcn_mfma_i32_32x32x32_i8(a0, b0, acc[0][0], 0, 0, 0);
            acc[0][1] = __builtin_amdgcn_mfma_i32_32x32x32_i8(a0, b1, acc[0][1], 0, 0, 0);
            acc[1][0] = __builtin_amdgcn_mfma_i32_32x32x32_i8(a1, b0, acc[1][0], 0, 0, 0);
            acc[1][1] = __builtin_amdgcn_mfma_i32_32x32x32_i8(a1, b1, acc[1][1], 0, 0, 0);
            acc[2][0] = __builtin_amdgcn_mfma_i32_32x32x32_i8(a2, b0, acc[2][0], 0, 0, 0);
            acc[2][1] = __builtin_amdgcn_mfma_i32_32x32x32_i8(a2, b1, acc[2][1], 0, 0, 0);
            acc[3][0] = __builtin_amdgcn_mfma_i32_32x32x32_i8(a3, b0, acc[3][0], 0, 0, 0);
            acc[3][1] = __builtin_amdgcn_mfma_i32_32x32x32_i8(a3, b1, acc[3][1], 0, 0, 0);
            __builtin_amdgcn_s_setprio(0);
        }

        // ---- tile boundary: next tile's buffer must be fully landed ----
        __builtin_amdgcn_sched_barrier(0);
        asm volatile("s_waitcnt vmcnt(0)" ::: "memory");
        __builtin_amdgcn_s_barrier();
    }

    // Epilogue: 32x32 C/D layout col(n) = lane&31, row(m) = (reg&3)+8*(reg>>2)+4*hi
#pragma unroll
    for (int mi = 0; mi < 4; ++mi) {
        const int mbase = bm * 256 + wm + mi * 32 + 4 * hi;
        float sxv[16];
#pragma unroll
        for (int r = 0; r < 16; ++r)
            sxv[r] = sx[mbase + (r & 3) + 8 * (r >> 2)];
#pragma unroll
        for (int nj = 0; nj < 2; ++nj) {
            const int n = bn * 256 + wn + nj * 32 + r5;
            const float swn = sw[n];
            const float bqn = bq[n];
#pragma unroll
            for (int r = 0; r < 16; ++r) {
                const int m = mbase + (r & 3) + 8 * (r >> 2);
                out[(size_t)m * N + n] = (float)acc[mi][nj][r] * sxv[r] * swn + bqn;
            }
        }
    }
}

extern "C" void kernel_launch(void* const* d_in, const int* in_sizes, int n_in,
                              void* d_out, int out_size, void* d_ws, size_t ws_size,
                              hipStream_t stream) {
    const float* x      = (const float*)d_in[0];  // [4,2048,4096]
    const float* weight = (const float*)d_in[1];  // [4096,4096]
    const float* bias   = (const float*)d_in[2];  // [4096]
    const float* scales = (const float*)d_in[3];  // [4096]
    float* out = (float*)d_out;                   // [4,2048,4096]

    char* ws = (char*)d_ws;
    signed char* qx = (signed char*)ws;                       // 8192*4096 = 33554432 B
    signed char* qw = (signed char*)(ws + 33554432);          // 4096*4096 = 16777216 B
    float* sx = (float*)(ws + 50331648);                      // 8192*4 B
    float* sw = (float*)(ws + 50364416);                      // 4096*4 B
    float* bq = (float*)(ws + 50380800);                      // 4096*4 B

    quant_all<<<MTOK + DDIM, 256, 0, stream>>>(x, weight, scales, qx, sx, qw, sw, bias, bq);

    dim3 grid(DDIM / 256, MTOK / 256);  // (16, 32) = 512 blocks, 1 per CU x 2 passes
    gemm_i8<<<grid, 512, 0, stream>>>(qx, qw, sx, sw, bq, out);
}

// Round 3
// 404.194 us; speedup vs baseline: 1.0462x; 1.0163x over previous
//
#include <hip/hip_runtime.h>
#include <stdint.h>

// Problem constants (B=4, S=2048, D=4096)
#define DDIM 4096
#define MTOK 8192
#define NT64 (DDIM / 64)     // 64 K-tiles of BK=64

typedef __attribute__((ext_vector_type(4))) int i32x4;
typedef __attribute__((ext_vector_type(16))) int i32x16;

__device__ __forceinline__ void async16(const void* g, void* l) {
    __builtin_amdgcn_global_load_lds(
        (const __attribute__((address_space(1))) unsigned int*)g,
        (__attribute__((address_space(3))) unsigned int*)l,
        16, 0, 0);
}

// ---------------- Fused quantization kernel (unchanged, ~35 us, HBM roofline) ----
__global__ __launch_bounds__(256) void quant_all(
    const float* __restrict__ x, const float* __restrict__ weight,
    const float* __restrict__ scales,
    signed char* __restrict__ qx, float* __restrict__ sx,
    signed char* __restrict__ qw, float* __restrict__ sw,
    const float* __restrict__ bias, float* __restrict__ bq)
{
    __shared__ float red[4];
    const int tid = threadIdx.x;
    const bool is_x = blockIdx.x < MTOK;
    const int row = is_x ? blockIdx.x : (blockIdx.x - MTOK);
    const float* src = is_x ? (x + (size_t)row * DDIM) : (weight + (size_t)row * DDIM);
    signed char* q = is_x ? qx : qw;
    float* srow = is_x ? sx : sw;

    const float4* s4 = (const float4*)scales;
    const float4* x4 = (const float4*)src;

    float4 v[4];
    float am = 0.0f;
#pragma unroll
    for (int j = 0; j < 4; ++j) {
        float4 a = x4[tid + j * 256];
        float4 s = s4[tid + j * 256];
        float4 r;
        if (is_x) { r.x = a.x * s.x; r.y = a.y * s.y; r.z = a.z * s.z; r.w = a.w * s.w; }
        else      { r.x = a.x / s.x; r.y = a.y / s.y; r.z = a.z / s.z; r.w = a.w / s.w; }
        v[j] = r;
        am = fmaxf(am, fmaxf(fmaxf(fabsf(r.x), fabsf(r.y)),
                             fmaxf(fabsf(r.z), fabsf(r.w))));
    }
#pragma unroll
    for (int off = 32; off > 0; off >>= 1)
        am = fmaxf(am, __shfl_xor(am, off, 64));
    if ((tid & 63) == 0) red[tid >> 6] = am;
    __syncthreads();
    am = fmaxf(fmaxf(red[0], red[1]), fmaxf(red[2], red[3]));
    am = fmaxf(am, 1e-8f);

    const float sc = 127.0f / am;
    uint32_t* qrow = (uint32_t*)(q + (size_t)row * DDIM);
#pragma unroll
    for (int j = 0; j < 4; ++j) {
        int q0 = (int)fminf(127.0f, fmaxf(-127.0f, rintf(v[j].x * sc)));
        int q1 = (int)fminf(127.0f, fmaxf(-127.0f, rintf(v[j].y * sc)));
        int q2 = (int)fminf(127.0f, fmaxf(-127.0f, rintf(v[j].z * sc)));
        int q3 = (int)fminf(127.0f, fmaxf(-127.0f, rintf(v[j].w * sc)));
        qrow[tid + j * 256] = (uint32_t)(q0 & 0xff) | ((uint32_t)(q1 & 0xff) << 8) |
                              ((uint32_t)(q2 & 0xff) << 16) | ((uint32_t)(q3 & 0xff) << 24);
    }
    if (tid == 0) {
        srow[row] = am * (1.0f / 127.0f);
        if (!is_x) bq[row] = bias[row] / scales[row];
    }
}

// ---------------- int8 GEMM: 256x256 tile, BK=64 ring-4, counted vmcnt ----------
// out[m,n] = (sum_k qx[m,k]*qw[n,k]) * sx[m]*sw[n] + bq[n]
//
// R3: depth-3 prefetch ring (T4 counted vmcnt -- the m218 lever R1/R2 lacked;
// a double buffer structurally forces vmcnt(0) at each tile, ring-4 doesn't).
//   512 thr = 8 waves 2(M)x4(N), wave C = 128x64 = 4x2 of 32x32x32 i8 MFMAs.
//   LDS = 4 ring slots x (A 16KB + B 16KB) = 128 KiB. Per BK=64 tile:
//     s_waitcnt vmcnt(8)        <- tile h landed (8 = loads of h+1,h+2 in
//                                  flight; vmcnt retires in order). NEVER 0
//                                  in the main loop.
//     s_barrier                 <- all waves' writes of slot h published
//     12 ds_read_b128 (ks0 group, then ks1 group; order pinned)
//     4  async16 -> slot (h+3)&3  (= slot h-1: its reads completed before
//                                  this barrier -- every wave did lgkmcnt(0)
//                                  in tile h-1 before reaching barrier h)
//     lgkmcnt(6) ; 8 MFMA (ks0) ; lgkmcnt(0) ; 8 MFMA (ks1)   [rule-18 fences]
//
// LDS geometry: [256][64] per matrix per slot, 64 B rows. 16 B chunk c of row
// r stored at position c ^ ((r>>1)&3). Bank check (64 lanes = 32 rows x 2
// k-halves): per row-parity the XOR spreads positions uniformly -> each
// 4-bank group serves 8 lanes x 16 B = 128 B -> ds_read_b128 runs at its
// 8-cyc floor, bank-balanced. Same involution on stage (global-address side,
// since global_load_lds dst is base+lane*16) and on read -> contraction
// unchanged (permutation resolved at read time, per-row on both A and B).
__global__ __launch_bounds__(512, 2) void gemm_i8(
    const signed char* __restrict__ qx, const signed char* __restrict__ qw,
    const float* __restrict__ sx, const float* __restrict__ sw,
    const float* __restrict__ bq, float* __restrict__ out)
{
    __shared__ __align__(16) signed char sA[4][256 * 64];
    __shared__ __align__(16) signed char sB[4][256 * 64];

    const int K = DDIM, N = DDIM;
    const int tid  = threadIdx.x;
    const int bm   = blockIdx.y;
    const int bn   = blockIdx.x;
    const int wave = tid >> 6;
    const int lane = tid & 63;
    const int wm   = (wave >> 2) << 7;  // 0 or 128
    const int wn   = (wave & 3) << 6;   // 0,64,128,192
    const int r5   = lane & 31;
    const int hi   = lane >> 5;
    const int xr   = (r5 >> 1) & 3;     // read-side row swizzle term

    const signed char* Ab = qx + (size_t)bm * 256 * K;
    const signed char* Bb = qw + (size_t)bn * 256 * K;

    // Stage addressing: thread writes LDS bytes tid*16 (+8192), i.e. position
    // (row = tid>>2 [+128], pos = tid&3); fetches global chunk kc = pos ^ f(row),
    // f(row) = (row>>1)&3 = (tid>>3)&3 (identical for row and row+128).
    const int g_row = tid >> 2;
    const int kc    = (tid & 3) ^ ((tid >> 3) & 3);
    const int dst0  = tid * 16;

    // Read byte offsets within a 64 B row: pos = (ks*2+hi) ^ xr, ks in {0,1}
    const int off0 = (((0 * 2 + hi) ^ xr) << 4);
    const int off1 = (((1 * 2 + hi) ^ xr) << 4);
    // Row byte bases
    const int rA0 = (wm +      r5) * 64;
    const int rA1 = (wm + 32 + r5) * 64;
    const int rA2 = (wm + 64 + r5) * 64;
    const int rA3 = (wm + 96 + r5) * 64;
    const int rB0 = (wn +      r5) * 64;
    const int rB1 = (wn + 32 + r5) * 64;

    i32x16 acc[4][2] = {};

#define STAGE(t) do {                                                        \
        const int _s = (t) & 3;                                              \
        const size_t _k = (size_t)(t) * 64 + kc * 16;                        \
        async16(Ab + (size_t)g_row         * K + _k, &sA[_s][dst0]);         \
        async16(Ab + (size_t)(g_row + 128) * K + _k, &sA[_s][dst0 + 8192]);  \
        async16(Bb + (size_t)g_row         * K + _k, &sB[_s][dst0]);         \
        async16(Bb + (size_t)(g_row + 128) * K + _k, &sB[_s][dst0 + 8192]);  \
    } while (0)

    // Prologue: stage tiles 0,1,2 (12 loads in flight).
    STAGE(0);
    STAGE(1);
    STAGE(2);

    for (int h = 0; h < NT64; ++h) {
        // Counted wait: tile h's 4 loads are the oldest; <=8 outstanding
        // (tiles h+1,h+2) implies h retired. Tail tiles need smaller counts.
        if (h <= NT64 - 3)      asm volatile("s_waitcnt vmcnt(8)" ::: "memory");
        else if (h == NT64 - 2) asm volatile("s_waitcnt vmcnt(4)" ::: "memory");
        else                    asm volatile("s_waitcnt vmcnt(0)" ::: "memory");
        __builtin_amdgcn_s_barrier();
        __builtin_amdgcn_sched_barrier(0);

        const signed char* a = sA[h & 3];
        const signed char* b = sB[h & 3];

        // ks=0 read group (issue order pinned ahead of ks=1 for lgkmcnt(6))
        i32x4 a00 = *(const i32x4*)&a[rA0 + off0];
        i32x4 a10 = *(const i32x4*)&a[rA1 + off0];
        i32x4 a20 = *(const i32x4*)&a[rA2 + off0];
        i32x4 a30 = *(const i32x4*)&a[rA3 + off0];
        i32x4 b00 = *(const i32x4*)&b[rB0 + off0];
        i32x4 b10 = *(const i32x4*)&b[rB1 + off0];
        __builtin_amdgcn_sched_barrier(0);
        // ks=1 read group
        i32x4 a01 = *(const i32x4*)&a[rA0 + off1];
        i32x4 a11 = *(const i32x4*)&a[rA1 + off1];
        i32x4 a21 = *(const i32x4*)&a[rA2 + off1];
        i32x4 a31 = *(const i32x4*)&a[rA3 + off1];
        i32x4 b01 = *(const i32x4*)&b[rB0 + off1];
        i32x4 b11 = *(const i32x4*)&b[rB1 + off1];
        __builtin_amdgcn_sched_barrier(0);

        // Prefetch tile h+3 into ring slot (h+3)&3 (WAR-safe, see header).
        if (h + 3 < NT64) STAGE(h + 3);
        __builtin_amdgcn_sched_barrier(0);

        asm volatile("s_waitcnt lgkmcnt(6)" ::: "memory");  // ks0 group landed
        __builtin_amdgcn_sched_barrier(0);
        __builtin_amdgcn_s_setprio(1);
        acc[0][0] = __builtin_amdgcn_mfma_i32_32x32x32_i8(a00, b00, acc[0][0], 0, 0, 0);
        acc[0][1] = __builtin_amdgcn_mfma_i32_32x32x32_i8(a00, b10, acc[0][1], 0, 0, 0);
        acc[1][0] = __builtin_amdgcn_mfma_i32_32x32x32_i8(a10, b00, acc[1][0], 0, 0, 0);
        acc[1][1] = __builtin_amdgcn_mfma_i32_32x32x32_i8(a10, b10, acc[1][1], 0, 0, 0);
        acc[2][0] = __builtin_amdgcn_mfma_i32_32x32x32_i8(a20, b00, acc[2][0], 0, 0, 0);
        acc[2][1] = __builtin_amdgcn_mfma_i32_32x32x32_i8(a20, b10, acc[2][1], 0, 0, 0);
        acc[3][0] = __builtin_amdgcn_mfma_i32_32x32x32_i8(a30, b00, acc[3][0], 0, 0, 0);
        acc[3][1] = __builtin_amdgcn_mfma_i32_32x32x32_i8(a30, b10, acc[3][1], 0, 0, 0);
        __builtin_amdgcn_s_setprio(0);
        __builtin_amdgcn_sched_barrier(0);

        asm volatile("s_waitcnt lgkmcnt(0)" ::: "memory");  // ks1 group landed
        __builtin_amdgcn_sched_barrier(0);
        __builtin_amdgcn_s_setprio(1);
        acc[0][0] = __builtin_amdgcn_mfma_i32_32x32x32_i8(a01, b01, acc[0][0], 0, 0, 0);
        acc[0][1] = __builtin_amdgcn_mfma_i32_32x32x32_i8(a01, b11, acc[0][1], 0, 0, 0);
        acc[1][0] = __builtin_amdgcn_mfma_i32_32x32x32_i8(a11, b01, acc[1][0], 0, 0, 0);
        acc[1][1] = __builtin_amdgcn_mfma_i32_32x32x32_i8(a11, b11, acc[1][1], 0, 0, 0);
        acc[2][0] = __builtin_amdgcn_mfma_i32_32x32x32_i8(a21, b01, acc[2][0], 0, 0, 0);
        acc[2][1] = __builtin_amdgcn_mfma_i32_32x32x32_i8(a21, b11, acc[2][1], 0, 0, 0);
        acc[3][0] = __builtin_amdgcn_mfma_i32_32x32x32_i8(a31, b01, acc[3][0], 0, 0, 0);
        acc[3][1] = __builtin_amdgcn_mfma_i32_32x32x32_i8(a31, b11, acc[3][1], 0, 0, 0);
        __builtin_amdgcn_s_setprio(0);
    }
#undef STAGE

    // Epilogue: 32x32 C/D layout col(n) = lane&31, row(m) = (reg&3)+8*(reg>>2)+4*hi
#pragma unroll
    for (int mi = 0; mi < 4; ++mi) {
        const int mbase = bm * 256 + wm + mi * 32 + 4 * hi;
        float sxv[16];
#pragma unroll
        for (int r = 0; r < 16; ++r)
            sxv[r] = sx[mbase + (r & 3) + 8 * (r >> 2)];
#pragma unroll
        for (int nj = 0; nj < 2; ++nj) {
            const int n = bn * 256 + wn + nj * 32 + r5;
            const float swn = sw[n];
            const float bqn = bq[n];
#pragma unroll
            for (int r = 0; r < 16; ++r) {
                const int m = mbase + (r & 3) + 8 * (r >> 2);
                out[(size_t)m * N + n] = (float)acc[mi][nj][r] * sxv[r] * swn + bqn;
            }
        }
    }
}

extern "C" void kernel_launch(void* const* d_in, const int* in_sizes, int n_in,
                              void* d_out, int out_size, void* d_ws, size_t ws_size,
                              hipStream_t stream) {
    const float* x      = (const float*)d_in[0];  // [4,2048,4096]
    const float* weight = (const float*)d_in[1];  // [4096,4096]
    const float* bias   = (const float*)d_in[2];  // [4096]
    const float* scales = (const float*)d_in[3];  // [4096]
    float* out = (float*)d_out;                   // [4,2048,4096]

    char* ws = (char*)d_ws;
    signed char* qx = (signed char*)ws;                       // 8192*4096 = 33554432 B
    signed char* qw = (signed char*)(ws + 33554432);          // 4096*4096 = 16777216 B
    float* sx = (float*)(ws + 50331648);                      // 8192*4 B
    float* sw = (float*)(ws + 50364416);                      // 4096*4 B
    float* bq = (float*)(ws + 50380800);                      // 4096*4 B

    quant_all<<<MTOK + DDIM, 256, 0, stream>>>(x, weight, scales, qx, sx, qw, sw, bias, bq);

    dim3 grid(DDIM / 256, MTOK / 256);  // (16, 32) = 512 blocks, 1 per CU x 2 passes
    gemm_i8<<<grid, 512, 0, stream>>>(qx, qw, sx, sw, bq, out);
}